// Round 1
// baseline (616.344 us; speedup 1.0000x reference)
//
#include <hip/hip_runtime.h>
#include <math.h>

// Problem constants (VQ2): B=16384, D_IN=512, H=64, C=256, K=2048
#define NB 16384
#define NDIN 512
#define NH 64
#define NC 256
#define NK 2048

// ---------------------------------------------------------------------------
// Generic tiled fp32 GEMM: out = act(A @ W + bias)
//   A: [M][Kd] row-major, W: [Kd][N] row-major, out: [M][N]
//   BM=BN=64, BK=16, 256 threads, 4x4 micro-tile per thread.
// ---------------------------------------------------------------------------
template <int RELU>
__global__ __launch_bounds__(256) void gemm_bias_act(
    const float* __restrict__ A, const float* __restrict__ W,
    const float* __restrict__ bias, float* __restrict__ out,
    int M, int Kd, int N) {
  __shared__ float As[16][68];  // [kk][m], pad 68 -> 2-way max bank aliasing
  __shared__ float Bs[16][68];  // [kk][n]
  const int bm = blockIdx.x * 64;
  const int bn = blockIdx.y * 64;
  const int t = threadIdx.x;
  const int tm = (t >> 4) << 2;
  const int tn = (t & 15) << 2;
  float acc[4][4] = {};
  for (int k0 = 0; k0 < Kd; k0 += 16) {
#pragma unroll
    for (int i = 0; i < 4; ++i) {
      int idx = t + i * 256;
      int m = idx >> 4, kk = idx & 15;  // consecutive lanes -> consecutive kk (coalesced 64B)
      As[kk][m] = A[(size_t)(bm + m) * Kd + (k0 + kk)];
    }
#pragma unroll
    for (int i = 0; i < 4; ++i) {
      int idx = t + i * 256;
      int kk = idx >> 6, n = idx & 63;  // consecutive lanes -> consecutive n (coalesced 256B)
      Bs[kk][n] = W[(size_t)(k0 + kk) * N + (bn + n)];
    }
    __syncthreads();
#pragma unroll
    for (int kk = 0; kk < 16; ++kk) {
      const float4 a4 = *(const float4*)&As[kk][tm];
      const float4 b4 = *(const float4*)&Bs[kk][tn];
      const float av[4] = {a4.x, a4.y, a4.z, a4.w};
      const float bv[4] = {b4.x, b4.y, b4.z, b4.w};
#pragma unroll
      for (int i = 0; i < 4; ++i)
#pragma unroll
        for (int j = 0; j < 4; ++j) acc[i][j] = fmaf(av[i], bv[j], acc[i][j]);
    }
    __syncthreads();
  }
#pragma unroll
  for (int i = 0; i < 4; ++i) {
    float4 o;
    float b0 = bias[bn + tn + 0], b1 = bias[bn + tn + 1];
    float b2 = bias[bn + tn + 2], b3 = bias[bn + tn + 3];
    o.x = acc[i][0] + b0;
    o.y = acc[i][1] + b1;
    o.z = acc[i][2] + b2;
    o.w = acc[i][3] + b3;
    if (RELU) {
      o.x = fmaxf(o.x, 0.f);
      o.y = fmaxf(o.y, 0.f);
      o.z = fmaxf(o.z, 0.f);
      o.w = fmaxf(o.w, 0.f);
    }
    *(float4*)&out[(size_t)(bm + tm + i) * N + (bn + tn)] = o;
  }
}

// ---------------------------------------------------------------------------
// S-GEMM: S[b][k] = -(rn[b] + pn[k] - 2*mu[b]·protos[k])  (== neg_d, no gumbel)
// B operand is protos [NK][NC] loaded transposed (same pattern as A).
// ---------------------------------------------------------------------------
__global__ __launch_bounds__(256) void gemm_S(
    const float* __restrict__ mu, const float* __restrict__ protos,
    const float* __restrict__ rn, const float* __restrict__ pn,
    float* __restrict__ S) {
  __shared__ float As[16][68];
  __shared__ float Bs[16][68];
  const int bm = blockIdx.x * 64;
  const int bn = blockIdx.y * 64;
  const int t = threadIdx.x;
  const int tm = (t >> 4) << 2;
  const int tn = (t & 15) << 2;
  float acc[4][4] = {};
  for (int k0 = 0; k0 < NC; k0 += 16) {
#pragma unroll
    for (int i = 0; i < 4; ++i) {
      int idx = t + i * 256;
      int m = idx >> 4, kk = idx & 15;
      As[kk][m] = mu[(size_t)(bm + m) * NC + (k0 + kk)];
      Bs[kk][m] = protos[(size_t)(bn + m) * NC + (k0 + kk)];
    }
    __syncthreads();
#pragma unroll
    for (int kk = 0; kk < 16; ++kk) {
      const float4 a4 = *(const float4*)&As[kk][tm];
      const float4 b4 = *(const float4*)&Bs[kk][tn];
      const float av[4] = {a4.x, a4.y, a4.z, a4.w};
      const float bv[4] = {b4.x, b4.y, b4.z, b4.w};
#pragma unroll
      for (int i = 0; i < 4; ++i)
#pragma unroll
        for (int j = 0; j < 4; ++j) acc[i][j] = fmaf(av[i], bv[j], acc[i][j]);
    }
    __syncthreads();
  }
  float p0 = pn[bn + tn + 0], p1 = pn[bn + tn + 1];
  float p2 = pn[bn + tn + 2], p3 = pn[bn + tn + 3];
#pragma unroll
  for (int i = 0; i < 4; ++i) {
    float rni = rn[bm + tm + i];
    float4 o;
    o.x = 2.0f * acc[i][0] - (rni + p0);
    o.y = 2.0f * acc[i][1] - (rni + p1);
    o.z = 2.0f * acc[i][2] - (rni + p2);
    o.w = 2.0f * acc[i][3] - (rni + p3);
    *(float4*)&S[(size_t)(bm + tm + i) * NK + (bn + tn)] = o;
  }
}

// ---------------------------------------------------------------------------
// Row squared-norms for a [rows][256] matrix; one wave per row.
// ---------------------------------------------------------------------------
__global__ __launch_bounds__(256) void rownorm_kernel(const float* __restrict__ X,
                                                      float* __restrict__ out, int rows) {
  int wave = (int)((blockIdx.x * 256 + threadIdx.x) >> 6);
  int lane = threadIdx.x & 63;
  if (wave >= rows) return;
  const float* xr = X + (size_t)wave * 256;
  float s = 0.f;
#pragma unroll
  for (int j = 0; j < 4; ++j) {
    float v = xr[lane + j * 64];
    s = fmaf(v, v, s);
  }
  for (int off = 32; off > 0; off >>= 1) s += __shfl_xor(s, off);
  if (lane == 0) out[wave] = s;
}

// ---------------------------------------------------------------------------
// Row pass: per row b (one wave, 16 rows/wave, 64 rows/block, 256 blocks):
//   m = max_k S, Z = sum exp(S-m), logZ
//   am = argmax_k (S + gumbel)  (first-index tie-break, matches jnp.argmax)
//   out[b,:] = protos[am,:]          (exact fp32 copy)
//   seg_p[k] += exp(S-m-logZ) ; seg_l[k] += (S-m-logZ)   (per-wave LDS segs)
// then block combines segments and atomically adds to global column sums.
// ---------------------------------------------------------------------------
__global__ __launch_bounds__(256) void row_pass(
    const float* __restrict__ S, const float* __restrict__ gumbel,
    const float* __restrict__ protos, float* __restrict__ out,
    float* __restrict__ csp, float* __restrict__ csl) {
  __shared__ float seg_p[4][NK];
  __shared__ float seg_l[4][NK];
  const int t = threadIdx.x;
  const int w = t >> 6, lane = t & 63;
  for (int k = lane; k < NK; k += 64) {
    seg_p[w][k] = 0.f;
    seg_l[w][k] = 0.f;
  }
  // wave is lockstep: no sync needed before using its own private segment
  for (int r = 0; r < 16; ++r) {
    const int b = blockIdx.x * 64 + w * 16 + r;
    const float* Srow = S + (size_t)b * NK;
    const float* grow = gumbel + (size_t)b * NK;
    float s[32], g[32];
#pragma unroll
    for (int j = 0; j < 32; ++j) {
      s[j] = Srow[j * 64 + lane];
      g[j] = grow[j * 64 + lane];
    }
    // row max
    float m = -INFINITY;
#pragma unroll
    for (int j = 0; j < 32; ++j) m = fmaxf(m, s[j]);
    for (int off = 32; off > 0; off >>= 1) m = fmaxf(m, __shfl_xor(m, off));
    // Z
    float Z = 0.f;
#pragma unroll
    for (int j = 0; j < 32; ++j) Z += expf(s[j] - m);
    for (int off = 32; off > 0; off >>= 1) Z += __shfl_xor(Z, off);
    const float logZ = logf(Z);
    // argmax(S+g), ties -> smallest k (jnp.argmax first occurrence)
    float bv = -INFINITY;
    int bi = 0x7fffffff;
#pragma unroll
    for (int j = 0; j < 32; ++j) {
      float v = s[j] + g[j];
      if (v > bv) {  // strict: ascending j keeps smallest k within lane
        bv = v;
        bi = j * 64 + lane;
      }
    }
    for (int off = 32; off > 0; off >>= 1) {
      float ov = __shfl_xor(bv, off);
      int oi = __shfl_xor(bi, off);
      if (ov > bv || (ov == bv && oi < bi)) {
        bv = ov;
        bi = oi;
      }
    }
    // bi now identical on all lanes (total order -> associative reduce)
    // accumulate column sums
#pragma unroll
    for (int j = 0; j < 32; ++j) {
      float lp = s[j] - m - logZ;
      seg_l[w][j * 64 + lane] += lp;
      seg_p[w][j * 64 + lane] += expf(lp);
    }
    // gather proto row -> output (exact copy)
    const float4* pr = (const float4*)(protos + (size_t)bi * NC);
    float4* orow = (float4*)(out + (size_t)b * NC);
    orow[lane] = pr[lane];
  }
  __syncthreads();
  for (int k = t; k < NK; k += 256) {
    atomicAdd(&csp[k], seg_p[0][k] + seg_p[1][k] + seg_p[2][k] + seg_p[3][k]);
    atomicAdd(&csl[k], seg_l[0][k] + seg_l[1][k] + seg_l[2][k] + seg_l[3][k]);
  }
}

// ---------------------------------------------------------------------------
// Finalize: prior_k = csp[k]/B + 1e-6 ; mlp_k = csl[k]/B
//   capacity = sum_k prior*(log prior - mlp) ; ent = -sum prior log prior
//   loss = 0.01*capacity - 0.001*ent
// ---------------------------------------------------------------------------
__global__ __launch_bounds__(256) void finalize_kernel(const float* __restrict__ csp,
                                                       const float* __restrict__ csl,
                                                       float* __restrict__ out_loss) {
  const int t = threadIdx.x;
  double cap = 0.0, plp = 0.0;
  for (int k = t; k < NK; k += 256) {
    float prior = csp[k] * (1.0f / (float)NB) + 1e-6f;
    float logprior = logf(prior);
    float mlp = csl[k] * (1.0f / (float)NB);
    cap += (double)prior * ((double)logprior - (double)mlp);
    plp += (double)prior * (double)logprior;
  }
  __shared__ double s1[256], s2[256];
  s1[t] = cap;
  s2[t] = plp;
  __syncthreads();
  for (int off = 128; off > 0; off >>= 1) {
    if (t < off) {
      s1[t] += s1[t + off];
      s2[t] += s2[t + off];
    }
    __syncthreads();
  }
  if (t == 0) {
    // loss = 0.01*cap + (-0.001)*(-plp) = 0.01*cap + 0.001*plp
    out_loss[0] = (float)(0.01 * s1[0] + 0.001 * s2[0]);
  }
}

// ---------------------------------------------------------------------------
extern "C" void kernel_launch(void* const* d_in, const int* in_sizes, int n_in,
                              void* d_out, int out_size, void* d_ws, size_t ws_size,
                              hipStream_t stream) {
  const float* x = (const float*)d_in[0];
  const float* gumbel = (const float*)d_in[1];
  const float* W_emb = (const float*)d_in[2];
  const float* b_emb = (const float*)d_in[3];
  const float* W0 = (const float*)d_in[4];
  const float* b0 = (const float*)d_in[5];
  const float* W1 = (const float*)d_in[6];
  const float* b1 = (const float*)d_in[7];
  const float* W_mu = (const float*)d_in[8];
  const float* b_mu = (const float*)d_in[9];
  // d_in[10]=W_var, d_in[11]=b_var: _logvar unused downstream -> skipped
  const float* protos = (const float*)d_in[12];
  float* out = (float*)d_out;

  // workspace layout (floats). Total ~168 MB.
  float* h0 = (float*)d_ws;                  // [NB][64]
  float* h1 = h0 + (size_t)NB * NH;          // [NB][64]
  float* h2 = h1 + (size_t)NB * NH;          // [NB][256]
  float* mu = h2 + (size_t)NB * NC;          // [NB][256]
  float* S = mu + (size_t)NB * NC;           // [NB][2048]
  float* rn = S + (size_t)NB * NK;           // [NB]
  float* pn = rn + NB;                       // [NK]
  float* csp = pn + NK;                      // [NK]
  float* csl = csp + NK;                     // [NK]

  hipMemsetAsync(csp, 0, 2 * NK * sizeof(float), stream);

  dim3 blk(256);
  gemm_bias_act<0><<<dim3(NB / 64, 1), blk, 0, stream>>>(x, W_emb, b_emb, h0, NB, NDIN, NH);
  gemm_bias_act<1><<<dim3(NB / 64, 1), blk, 0, stream>>>(h0, W0, b0, h1, NB, NH, NH);
  gemm_bias_act<1><<<dim3(NB / 64, NC / 64), blk, 0, stream>>>(h1, W1, b1, h2, NB, NH, NC);
  gemm_bias_act<0><<<dim3(NB / 64, NC / 64), blk, 0, stream>>>(h2, W_mu, b_mu, mu, NB, NC, NC);
  rownorm_kernel<<<dim3(NB / 4), blk, 0, stream>>>(mu, rn, NB);
  rownorm_kernel<<<dim3(NK / 4), blk, 0, stream>>>(protos, pn, NK);
  gemm_S<<<dim3(NB / 64, NK / 64), blk, 0, stream>>>(mu, protos, rn, pn, S);
  row_pass<<<dim3(NB / 64), blk, 0, stream>>>(S, gumbel, protos, out, csp, csl);
  finalize_kernel<<<1, blk, 0, stream>>>(csp, csl, out + (size_t)NB * NC);
}

// Round 2
// 372.216 us; speedup vs baseline: 1.6559x; 1.6559x over previous
//
#include <hip/hip_runtime.h>
#include <math.h>

// Problem constants (VQ2): B=16384, D_IN=512, H=64, C=256, K=2048
#define NB 16384
#define NDIN 512
#define NH 64
#define NC 256
#define NK 2048

typedef __bf16 bf16;
typedef __bf16 bf16x4 __attribute__((ext_vector_type(4)));
typedef __bf16 bf16x8 __attribute__((ext_vector_type(8)));
typedef float f32x4 __attribute__((ext_vector_type(4)));

__device__ __forceinline__ void gload_lds16(const bf16* g, bf16* l) {
  __builtin_amdgcn_global_load_lds(
      (const __attribute__((address_space(1))) void*)g,
      (__attribute__((address_space(3))) void*)l, 16, 0, 0);
}

// ---------------------------------------------------------------------------
// Elementwise fp32 -> bf16 cast (n4 = count/4)
// ---------------------------------------------------------------------------
__global__ __launch_bounds__(256) void cast_f2b(const float* __restrict__ in,
                                                bf16* __restrict__ out, int n4) {
  int i = blockIdx.x * 256 + threadIdx.x;
  if (i >= n4) return;
  float4 v = ((const float4*)in)[i];
  bf16x4 o;
  o[0] = (bf16)v.x; o[1] = (bf16)v.y; o[2] = (bf16)v.z; o[3] = (bf16)v.w;
  ((bf16x4*)out)[i] = o;
}

// ---------------------------------------------------------------------------
// W [K][N] fp32 -> Wt [N][K] bf16 (tiny matrices, coalesced writes)
// ---------------------------------------------------------------------------
__global__ __launch_bounds__(256) void transpose_cast(const float* __restrict__ W,
                                                      bf16* __restrict__ Wt, int K, int N) {
  int i = blockIdx.x * 256 + threadIdx.x;
  if (i >= K * N) return;
  int n = i / K, k = i - n * K;
  Wt[i] = (bf16)W[k * N + n];
}

// ---------------------------------------------------------------------------
// protos fp32 [NK][NC] -> bf16 + pn (norm of the ROUNDED values, one wave/row)
// ---------------------------------------------------------------------------
__global__ __launch_bounds__(256) void cast_protos(const float* __restrict__ P,
                                                   bf16* __restrict__ Pb,
                                                   float* __restrict__ pn) {
  int wave = (int)((blockIdx.x * 256 + threadIdx.x) >> 6);
  int lane = threadIdx.x & 63;
  if (wave >= NK) return;
  float4 v = ((const float4*)(P + (size_t)wave * NC))[lane];
  bf16x4 o;
  o[0] = (bf16)v.x; o[1] = (bf16)v.y; o[2] = (bf16)v.z; o[3] = (bf16)v.w;
  ((bf16x4*)(Pb + (size_t)wave * NC))[lane] = o;
  float s = 0.f;
#pragma unroll
  for (int j = 0; j < 4; ++j) {
    float f = (float)o[j];
    s = fmaf(f, f, s);
  }
  for (int off = 32; off > 0; off >>= 1) s += __shfl_xor(s, off);
  if (lane == 0) pn[wave] = s;
}

// ---------------------------------------------------------------------------
// Row squared-norms of bf16 [rows][NC]; one wave per row.
// ---------------------------------------------------------------------------
__global__ __launch_bounds__(256) void rownorm_bf(const bf16* __restrict__ X,
                                                  float* __restrict__ out, int rows) {
  int wave = (int)((blockIdx.x * 256 + threadIdx.x) >> 6);
  int lane = threadIdx.x & 63;
  if (wave >= rows) return;
  bf16x4 v = ((const bf16x4*)(X + (size_t)wave * NC))[lane];
  float s = 0.f;
#pragma unroll
  for (int j = 0; j < 4; ++j) {
    float f = (float)v[j];
    s = fmaf(f, f, s);
  }
  for (int off = 32; off > 0; off >>= 1) s += __shfl_xor(s, off);
  if (lane == 0) out[wave] = s;
}

// ---------------------------------------------------------------------------
// MLP MFMA GEMM: out_bf16 = act(A @ Bt^T + bias)
//   A [M][K] bf16 row-major, Bt [N][K] bf16 row-major (pre-transposed weight)
//   BM=64, BN=64, BK=32; 4 waves, wave computes 64x16.
// ---------------------------------------------------------------------------
template <int RELU>
__global__ __launch_bounds__(256) void mfma_mlp(const bf16* __restrict__ A,
                                                const bf16* __restrict__ Bt,
                                                const float* __restrict__ bias,
                                                bf16* __restrict__ out,
                                                int M, int K, int N) {
  __shared__ __align__(16) bf16 As[64 * 32];
  __shared__ __align__(16) bf16 Bs[64 * 32];
  const int t = threadIdx.x;
  const int w = t >> 6, lane = t & 63;
  const int bm = blockIdx.x * 64, bn = blockIdx.y * 64;
  const int lm = lane & 15, kq = lane >> 4;
  const int r = t >> 2, seg = t & 3;
  f32x4 acc[4] = {};
  for (int k0 = 0; k0 < K; k0 += 32) {
    __syncthreads();
    *(uint4*)&As[r * 32 + seg * 8] = *(const uint4*)&A[(size_t)(bm + r) * K + k0 + seg * 8];
    *(uint4*)&Bs[r * 32 + seg * 8] = *(const uint4*)&Bt[(size_t)(bn + r) * K + k0 + seg * 8];
    __syncthreads();
    bf16x8 bfr = *(const bf16x8*)&Bs[(w * 16 + lm) * 32 + kq * 8];
#pragma unroll
    for (int mi = 0; mi < 4; ++mi) {
      bf16x8 afr = *(const bf16x8*)&As[(mi * 16 + lm) * 32 + kq * 8];
      acc[mi] = __builtin_amdgcn_mfma_f32_16x16x32_bf16(afr, bfr, acc[mi], 0, 0, 0);
    }
  }
  const int col = bn + w * 16 + lm;
  const float bv = bias[col];
#pragma unroll
  for (int mi = 0; mi < 4; ++mi) {
#pragma unroll
    for (int rg = 0; rg < 4; ++rg) {
      float v = acc[mi][rg] + bv;
      if (RELU) v = fmaxf(v, 0.f);
      out[(size_t)(bm + mi * 16 + kq * 4 + rg) * N + col] = (bf16)v;
    }
  }
}

// ---------------------------------------------------------------------------
// S-GEMM (MFMA): S[b][k] = 2*mu_bf[b]·p_bf[k] - rn[b] - pn[k]   (fp32 out)
//   128x128 tile, BK=32, global_load_lds width-16 staging (m97 structure).
// ---------------------------------------------------------------------------
__global__ __launch_bounds__(256) void gemm_S_mfma(const bf16* __restrict__ A,
                                                   const bf16* __restrict__ Bt,
                                                   const float* __restrict__ rn,
                                                   const float* __restrict__ pn,
                                                   float* __restrict__ S) {
  __shared__ __align__(16) bf16 As[128 * 32];
  __shared__ __align__(16) bf16 Bs[128 * 32];
  const int t = threadIdx.x;
  const int w = t >> 6, lane = t & 63;
  const int bm = blockIdx.x * 128, bn = blockIdx.y * 128;
  const int wm = (w >> 1) * 64, wn = (w & 1) * 64;
  const int lm = lane & 15, kq = lane >> 4;
  f32x4 acc[4][4] = {};
  for (int k0 = 0; k0 < NC; k0 += 32) {
    __syncthreads();
#pragma unroll
    for (int i = 0; i < 2; ++i) {
      int c = i * 256 + t;        // 16B chunk index; lds byte = c*16 (lane-contiguous)
      int r = c >> 2, seg = c & 3;
      gload_lds16(&A[(size_t)(bm + r) * NC + k0 + seg * 8], &As[c * 8]);
      gload_lds16(&Bt[(size_t)(bn + r) * NC + k0 + seg * 8], &Bs[c * 8]);
    }
    __syncthreads();
    bf16x8 a[4], b[4];
#pragma unroll
    for (int i = 0; i < 4; ++i) {
      a[i] = *(const bf16x8*)&As[(wm + i * 16 + lm) * 32 + kq * 8];
      b[i] = *(const bf16x8*)&Bs[(wn + i * 16 + lm) * 32 + kq * 8];
    }
#pragma unroll
    for (int mi = 0; mi < 4; ++mi)
#pragma unroll
      for (int ni = 0; ni < 4; ++ni)
        acc[mi][ni] = __builtin_amdgcn_mfma_f32_16x16x32_bf16(a[mi], b[ni], acc[mi][ni], 0, 0, 0);
  }
#pragma unroll
  for (int mi = 0; mi < 4; ++mi) {
#pragma unroll
    for (int rg = 0; rg < 4; ++rg) {
      int row = bm + wm + mi * 16 + kq * 4 + rg;
      float rv = rn[row];
#pragma unroll
      for (int ni = 0; ni < 4; ++ni) {
        int col = bn + wn + ni * 16 + lm;
        S[(size_t)row * NK + col] = 2.0f * acc[mi][ni][rg] - rv - pn[col];
      }
    }
  }
}

// ---------------------------------------------------------------------------
// Row pass: softmax stats + argmax(S+g) + proto gather + column sums.
// ---------------------------------------------------------------------------
__global__ __launch_bounds__(256) void row_pass(
    const float* __restrict__ S, const float* __restrict__ gumbel,
    const float* __restrict__ protos, float* __restrict__ out,
    float* __restrict__ csp, float* __restrict__ csl) {
  __shared__ float seg_p[4][NK];
  __shared__ float seg_l[4][NK];
  const int t = threadIdx.x;
  const int w = t >> 6, lane = t & 63;
  for (int k = lane; k < NK; k += 64) {
    seg_p[w][k] = 0.f;
    seg_l[w][k] = 0.f;
  }
  for (int r = 0; r < 16; ++r) {
    const int b = blockIdx.x * 64 + w * 16 + r;
    const float* Srow = S + (size_t)b * NK;
    const float* grow = gumbel + (size_t)b * NK;
    float s[32], g[32];
#pragma unroll
    for (int j = 0; j < 32; ++j) {
      s[j] = Srow[j * 64 + lane];
      g[j] = grow[j * 64 + lane];
    }
    float m = -INFINITY;
#pragma unroll
    for (int j = 0; j < 32; ++j) m = fmaxf(m, s[j]);
    for (int off = 32; off > 0; off >>= 1) m = fmaxf(m, __shfl_xor(m, off));
    float Z = 0.f;
#pragma unroll
    for (int j = 0; j < 32; ++j) Z += expf(s[j] - m);
    for (int off = 32; off > 0; off >>= 1) Z += __shfl_xor(Z, off);
    const float logZ = logf(Z);
    float bv = -INFINITY;
    int bi = 0x7fffffff;
#pragma unroll
    for (int j = 0; j < 32; ++j) {
      float v = s[j] + g[j];
      if (v > bv) {
        bv = v;
        bi = j * 64 + lane;
      }
    }
    for (int off = 32; off > 0; off >>= 1) {
      float ov = __shfl_xor(bv, off);
      int oi = __shfl_xor(bi, off);
      if (ov > bv || (ov == bv && oi < bi)) {
        bv = ov;
        bi = oi;
      }
    }
#pragma unroll
    for (int j = 0; j < 32; ++j) {
      float lp = s[j] - m - logZ;
      seg_l[w][j * 64 + lane] += lp;
      seg_p[w][j * 64 + lane] += expf(lp);
    }
    const float4* pr = (const float4*)(protos + (size_t)bi * NC);
    float4* orow = (float4*)(out + (size_t)b * NC);
    orow[lane] = pr[lane];
  }
  __syncthreads();
  for (int k = t; k < NK; k += 256) {
    atomicAdd(&csp[k], seg_p[0][k] + seg_p[1][k] + seg_p[2][k] + seg_p[3][k]);
    atomicAdd(&csl[k], seg_l[0][k] + seg_l[1][k] + seg_l[2][k] + seg_l[3][k]);
  }
}

// ---------------------------------------------------------------------------
__global__ __launch_bounds__(256) void finalize_kernel(const float* __restrict__ csp,
                                                       const float* __restrict__ csl,
                                                       float* __restrict__ out_loss) {
  const int t = threadIdx.x;
  double cap = 0.0, plp = 0.0;
  for (int k = t; k < NK; k += 256) {
    float prior = csp[k] * (1.0f / (float)NB) + 1e-6f;
    float logprior = logf(prior);
    float mlp = csl[k] * (1.0f / (float)NB);
    cap += (double)prior * ((double)logprior - (double)mlp);
    plp += (double)prior * (double)logprior;
  }
  __shared__ double s1[256], s2[256];
  s1[t] = cap;
  s2[t] = plp;
  __syncthreads();
  for (int off = 128; off > 0; off >>= 1) {
    if (t < off) {
      s1[t] += s1[t + off];
      s2[t] += s2[t + off];
    }
    __syncthreads();
  }
  if (t == 0) out_loss[0] = (float)(0.01 * s1[0] + 0.001 * s2[0]);
}

// ---------------------------------------------------------------------------
extern "C" void kernel_launch(void* const* d_in, const int* in_sizes, int n_in,
                              void* d_out, int out_size, void* d_ws, size_t ws_size,
                              hipStream_t stream) {
  const float* x = (const float*)d_in[0];
  const float* gumbel = (const float*)d_in[1];
  const float* W_emb = (const float*)d_in[2];
  const float* b_emb = (const float*)d_in[3];
  const float* W0 = (const float*)d_in[4];
  const float* b0 = (const float*)d_in[5];
  const float* W1 = (const float*)d_in[6];
  const float* b1 = (const float*)d_in[7];
  const float* W_mu = (const float*)d_in[8];
  const float* b_mu = (const float*)d_in[9];
  // d_in[10]=W_var, d_in[11]=b_var unused (logvar dead downstream)
  const float* protos = (const float*)d_in[12];
  float* out = (float*)d_out;

  // workspace layout
  float* S = (float*)d_ws;                       // [NB][NK] fp32
  float* rn = S + (size_t)NB * NK;               // [NB]
  float* pn = rn + NB;                           // [NK]
  float* csp = pn + NK;                          // [NK]
  float* csl = csp + NK;                         // [NK]
  bf16* xb = (bf16*)(csl + NK);                  // [NB][NDIN]
  bf16* h0b = xb + (size_t)NB * NDIN;            // [NB][NH]
  bf16* h1b = h0b + (size_t)NB * NH;             // [NB][NH]
  bf16* h2b = h1b + (size_t)NB * NH;             // [NB][NC]
  bf16* mub = h2b + (size_t)NB * NC;             // [NB][NC]
  bf16* pb = mub + (size_t)NB * NC;              // [NK][NC]
  bf16* wembT = pb + (size_t)NK * NC;            // [NH][NDIN]
  bf16* w0T = wembT + NDIN * NH;                 // [NH][NH]
  bf16* w1T = w0T + NH * NH;                     // [NC][NH]
  bf16* wmuT = w1T + NH * NC;                    // [NC][NC]

  hipMemsetAsync(csp, 0, 2 * NK * sizeof(float), stream);

  dim3 blk(256);
  cast_f2b<<<(NB * NDIN / 4 + 255) / 256, blk, 0, stream>>>(x, xb, NB * NDIN / 4);
  transpose_cast<<<(NDIN * NH + 255) / 256, blk, 0, stream>>>(W_emb, wembT, NDIN, NH);
  transpose_cast<<<(NH * NH + 255) / 256, blk, 0, stream>>>(W0, w0T, NH, NH);
  transpose_cast<<<(NH * NC + 255) / 256, blk, 0, stream>>>(W1, w1T, NH, NC);
  transpose_cast<<<(NC * NC + 255) / 256, blk, 0, stream>>>(W_mu, wmuT, NC, NC);
  cast_protos<<<NK / 4, blk, 0, stream>>>(protos, pb, pn);

  mfma_mlp<0><<<dim3(NB / 64, NH / 64), blk, 0, stream>>>(xb, wembT, b_emb, h0b, NB, NDIN, NH);
  mfma_mlp<1><<<dim3(NB / 64, NH / 64), blk, 0, stream>>>(h0b, w0T, b0, h1b, NB, NH, NH);
  mfma_mlp<1><<<dim3(NB / 64, NC / 64), blk, 0, stream>>>(h1b, w1T, b1, h2b, NB, NH, NC);
  mfma_mlp<0><<<dim3(NB / 64, NC / 64), blk, 0, stream>>>(h2b, wmuT, b_mu, mub, NB, NC, NC);

  rownorm_bf<<<NB / 4, blk, 0, stream>>>(mub, rn, NB);
  gemm_S_mfma<<<dim3(NB / 128, NK / 128), blk, 0, stream>>>(mub, pb, rn, pn, S);
  row_pass<<<dim3(NB / 64), blk, 0, stream>>>(S, gumbel, protos, out, csp, csl);
  finalize_kernel<<<1, blk, 0, stream>>>(csp, csl, out + (size_t)NB * NC);
}